// Round 4
// baseline (292.065 us; speedup 1.0000x reference)
//
#include <hip/hip_runtime.h>
#include <math.h>

#define B_     2
#define L_     768
#define SIN_   1280
#define SOUT_  32
#define DI_    64
#define DST_   16
#define DCONV_ 4
#define DTR_   2
#define NCH    96      // chunks per batch (chunk = 8 rows)
#define CH     8

// ---------------- workspace layout (float offsets) ----------------
// gate : [B*L][64]        off 0
// xs   : [B*L][64]        off 98304
// dtf  : [B*L][64]        off 196608
// Bws  : [B*L][16]        off 294912
// Cws  : [B*L][16]        off 319488
// Pst  : [B*NCH][64][16]  off 344064
// Lst  : [B*NCH][64][16]  off 442368
// total 540672 floats = 2.16 MB

// K1: fully fused front end. 192 blocks x 256 threads, one 8-row chunk each
// (+3-row halo recomputed for the conv).
// s_proj (k4-outer, rows-in-registers, direct global reads) -> in_proj ->
// conv+SiLU -> x_proj -> dt/softplus -> local chunk scan.
__global__ __launch_bounds__(256) void k_front(
    const float* __restrict__ s, const float* __restrict__ spw,
    const float* __restrict__ spb, const float* __restrict__ ipw,
    const float* __restrict__ convw, const float* __restrict__ convb,
    const float* __restrict__ xpw, const float* __restrict__ dtw,
    const float* __restrict__ dtb, const float* __restrict__ Alog,
    float* __restrict__ gate_o, float* __restrict__ xs_o,
    float* __restrict__ dtf_o, float* __restrict__ Bws,
    float* __restrict__ Cws, float* __restrict__ Pst, float* __restrict__ Lst)
{
    const int bc  = blockIdx.x;               // b*NCH + c
    const int b   = bc / NCH, c = bc - b * NCH;
    const int l0  = c * CH;
    const long rbase = (long)b * L_ + l0;
    const int tid = threadIdx.x;

    __shared__ float w2[128 * 33];            // in_proj_w, stride 33 (2-way = free)
    __shared__ float sxpw[64][34];            // x_proj_w transposed
    __shared__ float sdtw[128];
    __shared__ float su[11][SOUT_];           // s_proj out, rows l0-3 .. l0+7
    __shared__ float sx[11][DI_];             // conv input (in_proj x-half)
    __shared__ float sxs[CH][DI_];            // silu(conv)
    __shared__ float sxd[CH][34];             // x_proj out
    __shared__ float sdt[CH][DI_];
    __shared__ float sdx[CH][DI_];

    // stage weights (no sync needed until first use after syncthreads)
    for (int i = tid; i < 128 * 32; i += 256)
        w2[(i >> 5) * 33 + (i & 31)] = ipw[i];
    for (int i = tid; i < 34 * 64; i += 256)
        sxpw[i & 63][i >> 6] = xpw[i];
    if (tid < 128) sdtw[tid] = dtw[tid];

    // ---- P1: s_proj for 11 rows. thread = (fg 0..7, c 0..31); each thread
    // owns 4 features (fg, fg+8, fg+16, fg+24) x 11 rows, 32-way k-split.
    const int fg = tid >> 5;
    const int cc = tid & 31;
    float acc[11][4];
    #pragma unroll
    for (int r = 0; r < 11; ++r)
        #pragma unroll
        for (int j = 0; j < 4; ++j) acc[r][j] = 0.f;

    {
        const float4* s4   = (const float4*)s;
        const float4* spw4 = (const float4*)spw;
        const long sb4 = ((long)b * L_ + l0 - 3) * (SIN_ / 4);
        for (int i = 0; i < 10; ++i) {
            const int k4 = cc + 32 * i;
            float4 w0 = spw4[(long)(fg     ) * 320 + k4];
            float4 w1 = spw4[(long)(fg +  8) * 320 + k4];
            float4 wv = spw4[(long)(fg + 16) * 320 + k4];
            float4 w3 = spw4[(long)(fg + 24) * 320 + k4];
            #pragma unroll
            for (int r = 0; r < 11; ++r) {
                if (l0 - 3 + r >= 0) {
                    float4 a = s4[sb4 + (long)r * 320 + k4];
                    acc[r][0] = fmaf(a.x, w0.x, fmaf(a.y, w0.y, fmaf(a.z, w0.z, fmaf(a.w, w0.w, acc[r][0]))));
                    acc[r][1] = fmaf(a.x, w1.x, fmaf(a.y, w1.y, fmaf(a.z, w1.z, fmaf(a.w, w1.w, acc[r][1]))));
                    acc[r][2] = fmaf(a.x, wv.x, fmaf(a.y, wv.y, fmaf(a.z, wv.z, fmaf(a.w, wv.w, acc[r][2]))));
                    acc[r][3] = fmaf(a.x, w3.x, fmaf(a.y, w3.y, fmaf(a.z, w3.z, fmaf(a.w, w3.w, acc[r][3]))));
                }
            }
        }
    }
    #pragma unroll
    for (int r = 0; r < 11; ++r) {
        #pragma unroll
        for (int j = 0; j < 4; ++j) {
            float v = acc[r][j];
            v += __shfl_xor(v, 1);  v += __shfl_xor(v, 2);
            v += __shfl_xor(v, 4);  v += __shfl_xor(v, 8);
            v += __shfl_xor(v, 16);
            if (cc == 0) {
                int f = fg + 8 * j;
                su[r][f] = (l0 - 3 + r >= 0) ? v + spb[f] : 0.f;   // zero-pad rows
            }
        }
    }
    __syncthreads();

    // ---- P2: in_proj. x-half for 11 rows, gate for 8 own rows (direct to global).
    for (int it = tid; it < 11 * DI_; it += 256) {
        int r = it >> 6, j = it & 63;
        const float* w = &w2[j * 33];
        float a = 0.f;
        #pragma unroll
        for (int k = 0; k < SOUT_; ++k) a = fmaf(su[r][k], w[k], a);
        sx[r][j] = a;
    }
    for (int it = tid; it < CH * DI_; it += 256) {
        int r = it >> 6, j = it & 63;
        const float* w = &w2[(64 + j) * 33];
        float a = 0.f;
        #pragma unroll
        for (int k = 0; k < SOUT_; ++k) a = fmaf(su[r + 3][k], w[k], a);
        gate_o[rbase * DI_ + it] = a;
    }
    __syncthreads();

    // ---- P3: causal conv (kernel 4) + SiLU ----
    for (int it = tid; it < CH * DI_; it += 256) {
        int r = it >> 6, d = it & 63;
        float xc = convb[d];
        #pragma unroll
        for (int k = 0; k < DCONV_; ++k)
            xc = fmaf(sx[r + k][d], convw[d * 4 + k], xc);   // sx row r+k = l0+r-3+k
        float xv = xc / (1.f + expf(-xc));
        sxs[r][d] = xv;
        xs_o[rbase * DI_ + it] = xv;
    }
    __syncthreads();

    // ---- P4: x_proj: 8 rows x 34 outs, dot-64 ----
    for (int it = tid; it < CH * 34; it += 256) {
        int r = it / 34, o = it - r * 34;
        float a = 0.f;
        #pragma unroll
        for (int k = 0; k < DI_; ++k) a = fmaf(sxs[r][k], sxpw[k][o], a);
        sxd[r][o] = a;
    }
    __syncthreads();

    // ---- P5: dt path + B/C out ----
    for (int it = tid; it < CH * DI_; it += 256) {
        int r = it >> 6, d = it & 63;
        float dtv = fmaf(sxd[r][0], sdtw[2 * d], fmaf(sxd[r][1], sdtw[2 * d + 1], dtb[d]));
        dtv = dtv > 20.f ? dtv : log1pf(expf(dtv));   // softplus
        sdt[r][d] = dtv;
        sdx[r][d] = dtv * sxs[r][d];
        dtf_o[rbase * DI_ + it] = dtv;
    }
    if (tid < CH * DST_) {                     // 128
        int r = tid >> 4, n = tid & 15;
        Bws[rbase * DST_ + tid] = sxd[r][DTR_ + n];
        Cws[rbase * DST_ + tid] = sxd[r][DTR_ + DST_ + n];
    }
    __syncthreads();

    // ---- P6: local chunk scan: (d,n) = 1024 items, 4 per thread ----
    const int n = tid & 15, g = tid >> 4;      // g 0..15
    float P[4], hl[4], A2[4];
    #pragma unroll
    for (int q = 0; q < 4; ++q) {
        int d = g + 16 * q;
        A2[q] = -expf(Alog[d * DST_ + n]) * 1.44269504088896f;
        P[q] = 1.f; hl[q] = 0.f;
    }
    #pragma unroll
    for (int l = 0; l < CH; ++l) {
        float bv = sxd[l][DTR_ + n];
        #pragma unroll
        for (int q = 0; q < 4; ++q) {
            int d = g + 16 * q;
            float a = exp2f(sdt[l][d] * A2[q]);
            P[q] *= a;
            hl[q] = fmaf(a, hl[q], sdx[l][d] * bv);
        }
    }
    const long o0 = (long)bc * 1024 + g * 16 + n;
    #pragma unroll
    for (int q = 0; q < 4; ++q) {
        Pst[o0 + 256 * q] = P[q];
        Lst[o0 + 256 * q] = hl[q];
    }
}

// K2: fused carry + re-scan + D-skip + gate + out_proj.
// 192 blocks x 1024 threads. Each block walks its own P/L prefix (<=95
// coalesced fma steps over 1024 parallel chains), then re-scans its 8 rows.
__global__ __launch_bounds__(1024) void k_back(
    const float* __restrict__ dtf, const float* __restrict__ xs,
    const float* __restrict__ Bws, const float* __restrict__ Cws,
    const float* __restrict__ Alog, const float* __restrict__ Pst,
    const float* __restrict__ Lst, const float* __restrict__ gate,
    const float* __restrict__ Dv, const float* __restrict__ opw,
    float* __restrict__ sp)
{
    const int bc = blockIdx.x;
    const int b  = bc / NCH, c = bc - b * NCH;
    const int l0 = c * CH;
    const long rbase = (long)b * L_ + l0;
    const int tid = threadIdx.x;

    __shared__ float sB[CH][DST_], sC[CH][DST_];
    __shared__ float sdt[CH][DI_], sxsS[CH][DI_];
    __shared__ float sy[CH][65];
    __shared__ float sw[64][33];               // out_proj_w transposed, padded

    if (tid < CH * DI_) {                      // 512: dt
        sdt[tid >> 6][tid & 63] = dtf[rbase * DI_ + tid];
    } else {                                   // 512: xs
        int t = tid - CH * DI_;
        sxsS[t >> 6][t & 63] = xs[rbase * DI_ + t];
    }
    if (tid < CH * DST_) {                     // 128
        sB[tid >> 4][tid & 15] = Bws[rbase * DST_ + tid];
    } else if (tid < 2 * CH * DST_) {
        int t = tid - CH * DST_;
        sC[t >> 4][t & 15] = Cws[rbase * DST_ + t];
    }
    for (int i = tid; i < SOUT_ * DI_; i += 1024)
        sw[i & 63][i >> 6] = opw[i];

    // carry: walk prefix chunks of this batch. 1024 independent chains.
    float h = 0.f;
    {
        const long ebase = (long)b * NCH * 1024 + tid;
        #pragma unroll 4
        for (int c2 = 0; c2 < c; ++c2) {
            long o = ebase + (long)c2 * 1024;
            h = fmaf(Pst[o], h, Lst[o]);
        }
    }
    const int d = tid >> 4, n = tid & 15;
    float A2 = -expf(Alog[d * DST_ + n]) * 1.44269504088896f;
    __syncthreads();

    #pragma unroll
    for (int l = 0; l < CH; ++l) {
        float dtv = sdt[l][d];
        float a = exp2f(dtv * A2);
        h = fmaf(a, h, dtv * sxsS[l][d] * sB[l][n]);
        float y = h * sC[l][n];
        y += __shfl_xor(y, 1);
        y += __shfl_xor(y, 2);
        y += __shfl_xor(y, 4);
        y += __shfl_xor(y, 8);
        if (n == 0) sy[l][d] = y;
    }
    __syncthreads();

    // yv = (y + xs*D) * silu(gate)
    if (tid < CH * DI_) {                      // 512
        int r = tid >> 6, dd = tid & 63;
        float g  = gate[rbase * DI_ + tid];
        float yv = fmaf(sxsS[r][dd], Dv[dd], sy[r][dd]);
        sy[r][dd] = yv * (g / (1.f + expf(-g)));
    }
    __syncthreads();

    // sp = yv @ out_proj_w.T : 8 rows x 32 outs, 64-dot each
    if (tid < CH * SOUT_) {                    // 256
        int r = tid >> 5, o = tid & 31;
        float acc = 0.f;
        #pragma unroll
        for (int k = 0; k < DI_; ++k) acc = fmaf(sy[r][k], sw[k][o], acc);
        sp[rbase * SOUT_ + tid] = acc;
    }
}

// K3: z_prime[b,s,t,f] = z[b,s,t]*zw[f] + zb[f] + sp[b,s,f]*sp[b,t,f]
__global__ __launch_bounds__(256) void k_z(
    const float* __restrict__ z, const float* __restrict__ zw,
    const float* __restrict__ zb, const float* __restrict__ sp,
    float* __restrict__ zout)
{
    const int idx = blockIdx.x * 256 + threadIdx.x;   // < B*L*L*8 = 9437184
    const int bs  = idx / 6144;         // b*L + s   (6144 = L*8 float4s)
    const int rem = idx - bs * 6144;
    const int t   = rem >> 3;
    const int f4  = rem & 7;
    const int b   = bs / L_;

    float zval = z[(long)bs * L_ + t];
    float4 w4 = ((const float4*)zw)[f4];
    float4 b4 = ((const float4*)zb)[f4];
    float4 ss = ((const float4*)sp)[bs * 8 + f4];
    float4 st = ((const float4*)sp)[(b * L_ + t) * 8 + f4];
    float4 o;
    o.x = zval * w4.x + b4.x + ss.x * st.x;
    o.y = zval * w4.y + b4.y + ss.y * st.y;
    o.z = zval * w4.z + b4.z + ss.z * st.z;
    o.w = zval * w4.w + b4.w + ss.w * st.w;
    ((float4*)zout)[(long)idx] = o;
}

extern "C" void kernel_launch(void* const* d_in, const int* in_sizes, int n_in,
                              void* d_out, int out_size, void* d_ws, size_t ws_size,
                              hipStream_t stream) {
    const float* s     = (const float*)d_in[0];
    const float* z     = (const float*)d_in[1];
    const float* spw   = (const float*)d_in[2];
    const float* spb   = (const float*)d_in[3];
    const float* zw    = (const float*)d_in[4];
    const float* zb    = (const float*)d_in[5];
    const float* ipw   = (const float*)d_in[6];
    const float* convw = (const float*)d_in[7];
    const float* convb = (const float*)d_in[8];
    const float* xpw   = (const float*)d_in[9];
    const float* dtw   = (const float*)d_in[10];
    const float* dtb   = (const float*)d_in[11];
    const float* Alog  = (const float*)d_in[12];
    const float* Dv    = (const float*)d_in[13];
    const float* opw   = (const float*)d_in[14];

    float* out  = (float*)d_out;
    float* ws   = (float*)d_ws;
    float* gate = ws;
    float* xs   = ws + 98304;
    float* dtf  = ws + 196608;
    float* Bws  = ws + 294912;
    float* Cws  = ws + 319488;
    float* Pst  = ws + 344064;
    float* Lst  = ws + 442368;

    float* sp   = out;            // s_prime: first 49152 floats of d_out
    float* zout = out + 49152;    // z_prime: remaining 37748736 floats

    k_front<<<B_ * NCH, 256, 0, stream>>>(s, spw, spb, ipw, convw, convb, xpw,
                                          dtw, dtb, Alog, gate, xs, dtf,
                                          Bws, Cws, Pst, Lst);
    k_back <<<B_ * NCH, 1024, 0, stream>>>(dtf, xs, Bws, Cws, Alog, Pst, Lst,
                                           gate, Dv, opw, sp);
    k_z    <<<(B_ * L_ * L_ * 8) / 256, 256, 0, stream>>>(z, zw, zb, sp, zout);
}

// Round 6
// 258.476 us; speedup vs baseline: 1.1299x; 1.1299x over previous
//
#include <hip/hip_runtime.h>
#include <math.h>

#define B_     2
#define L_     768
#define SIN_   1280
#define SOUT_  32
#define DI_    64
#define DST_   16
#define DCONV_ 4
#define DTR_   2
#define NCH    48     // chunks per batch (chunk = 16 rows)
#define CH     16

typedef float nfloat4 __attribute__((ext_vector_type(4)));   // for nontemporal store

// ---------------- workspace layout (float offsets) ----------------
// xz   : [B*L][128]   off 0        (x = [:,0:64], gate = [:,64:128])
// xs   : [B*L][64]    off 196608
// dtf  : [B*L][64]    off 294912
// dtx  : [B*L][64]    off 393216
// Bws  : [B*L][16]    off 491520
// Cws  : [B*L][16]    off 516096
// ysc  : [B*L][64]    off 540672
// Pst  : [B*NCH][64][16] off 638976
// Lst  : [B*NCH][64][16] off 737280
// Hst  : [B*NCH][64][16] off 835584
// total 933888 floats = 3.74 MB (round-0 proven footprint)

// K1 (round-3 verified): s_proj then in_proj. 768 blocks x 256, 2 rows/block.
__global__ __launch_bounds__(256) void k_sproj(
    const float* __restrict__ s, const float* __restrict__ spw,
    const float* __restrict__ spb, const float* __restrict__ ipw,
    float* __restrict__ xz)
{
    __shared__ float srow[2][SIN_];
    __shared__ float w2[128 * 33];          // in_proj_w, stride 33
    __shared__ float u[2][SOUT_];
    const int tid = threadIdx.x;
    const int row0 = blockIdx.x * 2;

    for (int r = 0; r < 2; ++r) {
        const float4* src = (const float4*)(s + (long)(row0 + r) * SIN_);
        for (int i = tid; i < SIN_ / 4; i += 256)
            ((float4*)srow[r])[i] = src[i];
    }
    for (int i = tid; i < 128 * 32; i += 256)
        w2[(i >> 5) * 33 + (i & 31)] = ipw[i];
    __syncthreads();

    const int f = tid >> 3;      // 0..31 output feature
    const int c = tid & 7;       // 0..7  k-slice
    float p0 = 0.f, p1 = 0.f;
    const float4* w4p = (const float4*)(spw + (long)f * SIN_);
    const float4* a0p = (const float4*)srow[0];
    const float4* a1p = (const float4*)srow[1];
    for (int k4 = c; k4 < SIN_ / 4; k4 += 8) {
        float4 w  = w4p[k4];
        float4 a0 = a0p[k4];
        float4 a1 = a1p[k4];
        p0 = fmaf(a0.x, w.x, fmaf(a0.y, w.y, fmaf(a0.z, w.z, fmaf(a0.w, w.w, p0))));
        p1 = fmaf(a1.x, w.x, fmaf(a1.y, w.y, fmaf(a1.z, w.z, fmaf(a1.w, w.w, p1))));
    }
    #pragma unroll
    for (int m = 1; m <= 4; m <<= 1) {
        p0 += __shfl_xor(p0, m);
        p1 += __shfl_xor(p1, m);
    }
    if (c == 0) {
        float bb = spb[f];
        u[0][f] = p0 + bb;
        u[1][f] = p1 + bb;
    }
    __syncthreads();

    const int j = tid & 127;     // output channel of xz
    const int r = tid >> 7;      // 0..1
    float acc = 0.f;
    const float* wj = &w2[j * 33];
    #pragma unroll
    for (int k = 0; k < SOUT_; ++k) acc += u[r][k] * wj[k];
    xz[(long)(row0 + r) * 128 + j] = acc;
}

// K2: conv + SiLU + x_proj + dt path. 4 rows/block, 384 blocks.
// Weight matrices read directly from global (L2-resident) - no staging phase.
__global__ __launch_bounds__(256) void k_pre2(
    const float* __restrict__ xz, const float* __restrict__ convw,
    const float* __restrict__ convb, const float* __restrict__ xpw,
    const float* __restrict__ dtw, const float* __restrict__ dtb,
    float* __restrict__ xs_o, float* __restrict__ dtf_o,
    float* __restrict__ dtx_o, float* __restrict__ Bws, float* __restrict__ Cws)
{
    const int row0 = blockIdx.x * 4;
    const int b = row0 / L_, l = row0 - b * L_;    // 768%4==0: block in one batch
    const long rbase = (long)row0;
    const int tid = threadIdx.x;

    __shared__ float sx[7][DI_];    // xz x-half, rows l-3 .. l+3
    __shared__ float sxs[4][DI_];
    __shared__ float sxd[4][34];

    for (int i = tid; i < 7 * DI_; i += 256) {
        int j = i >> 6, d = i & 63;
        int ls = l - 3 + j;
        sx[j][d] = (ls >= 0) ? xz[(long)(b * L_ + ls) * 128 + d] : 0.f;
    }
    __syncthreads();

    // conv + SiLU: 4 rows x 64 d = 256, one per thread
    {
        int r = tid >> 6, d = tid & 63;
        float xc = convb[d];
        #pragma unroll
        for (int k = 0; k < DCONV_; ++k)
            xc = fmaf(sx[r + k][d], convw[d * 4 + k], xc);
        float xv = xc / (1.f + expf(-xc));
        sxs[r][d] = xv;
        xs_o[rbase * DI_ + tid] = xv;
    }
    __syncthreads();

    // x_proj: 4 rows x 34 outs, dot-64 (xpw direct from L2)
    if (tid < 4 * 34) {
        int r = tid / 34, o = tid - r * 34;
        const float* w = xpw + (long)o * DI_;
        float a = 0.f;
        #pragma unroll
        for (int k = 0; k < DI_; ++k) a = fmaf(sxs[r][k], w[k], a);
        sxd[r][o] = a;
    }
    __syncthreads();

    // dt path: 4 rows x 64 d
    {
        int r = tid >> 6, d = tid & 63;
        float dtv = fmaf(sxd[r][0], dtw[2 * d], fmaf(sxd[r][1], dtw[2 * d + 1], dtb[d]));
        dtv = dtv > 20.f ? dtv : log1pf(expf(dtv));   // softplus
        dtf_o[rbase * DI_ + tid] = dtv;
        dtx_o[rbase * DI_ + tid] = dtv * sxs[r][d];
    }
    // B/C out: 4 rows x 32
    if (tid < 128) {
        int r = tid >> 5, j = tid & 31;
        if (j < DST_) Bws[(rbase + r) * DST_ + j] = sxd[r][DTR_ + j];
        else          Cws[(rbase + r) * DST_ + (j - DST_)] = sxd[r][DTR_ + j];
    }
}

// K3 (round-2 verified): local chunk scan, (d,n) decomposition. 384 blocks.
__global__ __launch_bounds__(256) void k_scan_p1(
    const float* __restrict__ dtf, const float* __restrict__ dtx,
    const float* __restrict__ Bws, const float* __restrict__ Alog,
    float* __restrict__ Pst, float* __restrict__ Lst)
{
    const int blk = blockIdx.x;                // bc*4 + dq
    const int dq  = blk & 3;
    const int bc  = blk >> 2;                  // b*NCH + c
    const int b   = bc / NCH, c = bc - b * NCH;
    const int tid = threadIdx.x;
    const int dl  = tid >> 4, n = tid & 15;
    const int d   = dq * 16 + dl;
    const long base = (long)b * L_ + c * CH;

    __shared__ float sB[CH][16];
    __shared__ float sdt[CH][16];
    __shared__ float sdx[CH][16];

    if (tid < 64) ((float4*)sB)[tid] = ((const float4*)(Bws + base * DST_))[tid];
    {
        int l = tid >> 4, j = tid & 15;        // 16x16 = 256 exactly
        sdt[l][j] = dtf[(base + l) * DI_ + dq * 16 + j];
        sdx[l][j] = dtx[(base + l) * DI_ + dq * 16 + j];
    }
    float A2 = -expf(Alog[d * DST_ + n]) * 1.44269504088896f;
    float P = 1.f, hl = 0.f;
    __syncthreads();

    #pragma unroll
    for (int l = 0; l < CH; ++l) {
        float a = exp2f(sdt[l][dl] * A2);
        P *= a;
        hl = fmaf(a, hl, sdx[l][dl] * sB[l][n]);
    }
    long o = (long)bc * 1024 + dq * 256 + tid;   // = (bc*64 + d)*16 + n
    Pst[o] = P;
    Lst[o] = hl;
}

// K4 (round-2 verified): carry combine. 2048 chains, 48 steps.
__global__ __launch_bounds__(256) void k_carry(
    const float* __restrict__ Pst, const float* __restrict__ Lst,
    float* __restrict__ Hst)
{
    const int idx = blockIdx.x * 256 + threadIdx.x;   // 0..2047
    const int b = idx >> 10, e = idx & 1023;
    float H = 0.f;
    #pragma unroll 8
    for (int c = 0; c < NCH; ++c) {
        long o = ((long)(b * NCH + c)) * 1024 + e;
        Hst[o] = H;
        H = fmaf(Pst[o], H, Lst[o]);
    }
}

// K5: re-scan from chunk-start state, y = sum_n h*C via shuffle. 384 blocks.
__global__ __launch_bounds__(256) void k_rescan(
    const float* __restrict__ dtf, const float* __restrict__ dtx,
    const float* __restrict__ Bws, const float* __restrict__ Cws,
    const float* __restrict__ Alog, const float* __restrict__ Hst,
    float* __restrict__ ysc)
{
    const int blk = blockIdx.x;
    const int dq  = blk & 3;
    const int bc  = blk >> 2;
    const int b   = bc / NCH, c = bc - b * NCH;
    const int tid = threadIdx.x;
    const int dl  = tid >> 4, n = tid & 15;
    const int d   = dq * 16 + dl;
    const long base = (long)b * L_ + c * CH;

    __shared__ float sB[CH][16], sC[CH][16];
    __shared__ float sdt[CH][16], sdx[CH][16];

    if (tid < 64) {
        ((float4*)sB)[tid] = ((const float4*)(Bws + base * DST_))[tid];
        ((float4*)sC)[tid] = ((const float4*)(Cws + base * DST_))[tid];
    }
    {
        int l = tid >> 4, j = tid & 15;
        sdt[l][j] = dtf[(base + l) * DI_ + dq * 16 + j];
        sdx[l][j] = dtx[(base + l) * DI_ + dq * 16 + j];
    }
    float A2 = -expf(Alog[d * DST_ + n]) * 1.44269504088896f;
    float h = Hst[(long)bc * 1024 + dq * 256 + tid];
    __syncthreads();

    #pragma unroll
    for (int l = 0; l < CH; ++l) {
        float a = exp2f(sdt[l][dl] * A2);
        h = fmaf(a, h, sdx[l][dl] * sB[l][n]);
        float y = h * sC[l][n];
        y += __shfl_xor(y, 1);
        y += __shfl_xor(y, 2);
        y += __shfl_xor(y, 4);
        y += __shfl_xor(y, 8);
        if (n == 0) ysc[(base + l) * DI_ + d] = y;
    }
}

// K6 (round-0 verified): y = ysc + xs*D; y *= silu(gate); sp = y @ opw.T
__global__ __launch_bounds__(256) void k_epi(
    const float* __restrict__ ysc, const float* __restrict__ xs,
    const float* __restrict__ xz, const float* __restrict__ Dv,
    const float* __restrict__ opw, float* __restrict__ sp)
{
    const int row0 = blockIdx.x * 4;
    const int tid = threadIdx.x;
    const int r = tid >> 6, d = tid & 63;
    const int row = row0 + r;
    __shared__ float sy[4][DI_];
    __shared__ float sw[64][SOUT_];            // opw transposed

    for (int i = tid; i < SOUT_ * DI_; i += 256) {
        int f = i >> 6, k = i & 63;
        sw[k][f] = opw[i];
    }
    float g = xz[(long)row * 128 + DI_ + d];
    float yv = fmaf(xs[(long)row * DI_ + d], Dv[d], ysc[(long)row * DI_ + d]);
    yv *= g / (1.f + expf(-g));
    sy[r][d] = yv;
    __syncthreads();

    if (d < SOUT_) {
        float acc = 0.f;
        #pragma unroll
        for (int k = 0; k < DI_; ++k) acc = fmaf(sy[r][k], sw[k][d], acc);
        sp[(long)row * SOUT_ + d] = acc;
    }
}

// K7: z_prime[b,s,t,f] = z[b,s,t]*zw[f] + zb[f] + sp[b,s,f]*sp[b,t,f]
__global__ __launch_bounds__(256) void k_z(
    const float* __restrict__ z, const float* __restrict__ zw,
    const float* __restrict__ zb, const float* __restrict__ sp,
    float* __restrict__ zout)
{
    const int idx = blockIdx.x * 256 + threadIdx.x;   // < B*L*L*8 = 9437184
    const int bs  = idx / 6144;         // b*L + s   (6144 = L*8 float4s)
    const int rem = idx - bs * 6144;
    const int t   = rem >> 3;
    const int f4  = rem & 7;
    const int b   = bs / L_;

    float zval = z[(long)bs * L_ + t];
    float4 w4 = ((const float4*)zw)[f4];
    float4 b4 = ((const float4*)zb)[f4];
    float4 ss = ((const float4*)sp)[bs * 8 + f4];
    float4 st = ((const float4*)sp)[(b * L_ + t) * 8 + f4];
    nfloat4 o;
    o.x = zval * w4.x + b4.x + ss.x * st.x;
    o.y = zval * w4.y + b4.y + ss.y * st.y;
    o.z = zval * w4.z + b4.z + ss.z * st.z;
    o.w = zval * w4.w + b4.w + ss.w * st.w;
    __builtin_nontemporal_store(o, (nfloat4*)zout + (long)idx);
}

extern "C" void kernel_launch(void* const* d_in, const int* in_sizes, int n_in,
                              void* d_out, int out_size, void* d_ws, size_t ws_size,
                              hipStream_t stream) {
    const float* s     = (const float*)d_in[0];
    const float* z     = (const float*)d_in[1];
    const float* spw   = (const float*)d_in[2];
    const float* spb   = (const float*)d_in[3];
    const float* zw    = (const float*)d_in[4];
    const float* zb    = (const float*)d_in[5];
    const float* ipw   = (const float*)d_in[6];
    const float* convw = (const float*)d_in[7];
    const float* convb = (const float*)d_in[8];
    const float* xpw   = (const float*)d_in[9];
    const float* dtw   = (const float*)d_in[10];
    const float* dtb   = (const float*)d_in[11];
    const float* Alog  = (const float*)d_in[12];
    const float* Dv    = (const float*)d_in[13];
    const float* opw   = (const float*)d_in[14];

    float* out = (float*)d_out;
    float* ws  = (float*)d_ws;
    float* xz  = ws;
    float* xs  = ws + 196608;
    float* dtf = ws + 294912;
    float* dtx = ws + 393216;
    float* Bws = ws + 491520;
    float* Cws = ws + 516096;
    float* ysc = ws + 540672;
    float* Pst = ws + 638976;
    float* Lst = ws + 737280;
    float* Hst = ws + 835584;

    float* sp   = out;            // s_prime: first 49152 floats of d_out
    float* zout = out + 49152;    // z_prime: remaining 37748736 floats

    k_sproj  <<<(B_ * L_) / 2, 256, 0, stream>>>(s, spw, spb, ipw, xz);
    k_pre2   <<<(B_ * L_) / 4, 256, 0, stream>>>(xz, convw, convb, xpw, dtw, dtb,
                                                 xs, dtf, dtx, Bws, Cws);
    k_scan_p1<<<B_ * NCH * 4, 256, 0, stream>>>(dtf, dtx, Bws, Alog, Pst, Lst);
    k_carry  <<<8, 256, 0, stream>>>(Pst, Lst, Hst);
    k_rescan <<<B_ * NCH * 4, 256, 0, stream>>>(dtf, dtx, Bws, Cws, Alog, Hst, ysc);
    k_epi    <<<(B_ * L_) / 4, 256, 0, stream>>>(ysc, xs, xz, Dv, opw, sp);
    k_z      <<<(B_ * L_ * L_ * 8) / 256, 256, 0, stream>>>(z, zw, zb, sp, zout);
}